// Round 3
// baseline (1993.987 us; speedup 1.0000x reference)
//
#include <hip/hip_runtime.h>

#define NPTS 80000
#define MPTS 150000
#define NDPTS 10000
#define KOFF 27
#define C3 16
#define CP 259
#define C2 64
#define CM 80
#define CO 96

typedef __attribute__((ext_vector_type(8))) short short8;
typedef __attribute__((ext_vector_type(4))) float f32x4;

__device__ inline short bf16r(float f) {
  union { float f; unsigned u; } x{f};
  unsigned r = (x.u + 0x7fffu + ((x.u >> 16) & 1u)) >> 16;
  return (short)r;
}

// ---------------------------------------------------------------------------
// Weight prep: W[k][ci][n] fp32 -> fragment-ordered bf16
// WbfF[((k*KC+q)*NT+t)*512 + lane*8 + j], B-frag element:
// ci = q*32 + (lane>>4)*8 + j, n = t*16 + (lane&15); ci >= CIN zero-padded.
// ---------------------------------------------------------------------------
__global__ void wfrag_kernel(const float* __restrict__ W, short* __restrict__ WbfF,
                             int CIN, int COUT_, int KC) {
  const int NT = COUT_ / 16;
  int i = blockIdx.x * 256 + threadIdx.x;
  int total = KOFF * KC * NT * 512;
  if (i >= total) return;
  int j = i & 7, lane = (i >> 3) & 63;
  int rest = i >> 9;
  int t = rest % NT; rest /= NT;
  int q = rest % KC;
  int k = rest / KC;
  int ci = q * 32 + (lane >> 4) * 8 + j;
  int n = t * 16 + (lane & 15);
  float v = (ci < CIN) ? W[((size_t)k * CIN + ci) * COUT_ + n] : 0.f;
  WbfF[i] = bf16r(v);
}

// ---------------------------------------------------------------------------
// Wp prep: fp32 [259][64] -> bf16 fragment-ordered [q][t][lane][8], K->288.
// ---------------------------------------------------------------------------
__global__ void wpfrag_kernel(const float* __restrict__ Wp, short* __restrict__ WpF) {
  int i = blockIdx.x * 256 + threadIdx.x;
  if (i >= 9 * 4 * 64 * 8) return;
  int j = i & 7, lane = (i >> 3) & 63, t = (i >> 9) & 3, q = i >> 11;
  int k = q * 32 + (lane >> 4) * 8 + j;
  int n = t * 16 + (lane & 15);
  WpF[i] = (k < CP) ? bf16r(Wp[(size_t)k * C2 + n]) : (short)0;
}

// ---------------------------------------------------------------------------
// Kernel 1: conv3d (16->16) + bn_relu. Single barrier per k, depth-2 gather
// prefetch into a double-buffered fS.
// ---------------------------------------------------------------------------
__global__ __launch_bounds__(256) void conv3d_bnrelu_kernel(
    const float* __restrict__ x3d, const int* __restrict__ nbr,
    const float* __restrict__ W3d, const float* __restrict__ g3d,
    const float* __restrict__ b3d, float* __restrict__ y3d,
    float* __restrict__ mix, short* __restrict__ mixbf)
{
  __shared__ float wS[KOFF * C3 * C3];
  __shared__ float fS[2][16][C3];
  const int tid = threadIdx.x;
  const int base = blockIdx.x * 16;
  for (int e = tid; e < KOFF * C3 * C3; e += 256) wS[e] = W3d[e];
  const int r = tid >> 4, c = tid & 15;
  const int row = base + r;

  // depth-2 prefetch
  int i0 = nbr[row * KOFF + 0];
  float fv = (i0 >= 0) ? x3d[i0 * C3 + c] : 0.f;
  int i1 = nbr[row * KOFF + 1];
  float fvn = (i1 >= 0) ? x3d[i1 * C3 + c] : 0.f;

  float acc = 0.f;
  for (int k = 0; k < KOFF; ++k) {
    fS[k & 1][r][c] = fv;
    fv = fvn;
    if (k + 2 < KOFF) {
      int ix = nbr[row * KOFF + k + 2];
      fvn = (ix >= 0) ? x3d[ix * C3 + c] : 0.f;
    } else {
      fvn = 0.f;
    }
    __syncthreads();   // first iter also covers wS
    const float* wk = &wS[k * C3 * C3];
    #pragma unroll
    for (int ci = 0; ci < C3; ++ci)
      acc = fmaf(fS[k & 1][r][ci], wk[ci * C3 + c], acc);
  }
  float v = fmaxf(fmaf(acc, g3d[c], b3d[c]), 0.f);
  y3d[row * C3 + c] = v;
  mix[row * CM + c] = v;
  mixbf[row * CM + c] = bf16r(v);
}

// ---------------------------------------------------------------------------
// Kernel 2: gate/cross fusion. v2: all 32 f2d gathers issued up front
// (8KB in flight per wave), y3d staged to LDS cooperatively, 3-column tail
// parallelized across 96 threads (was a 3-thread serial straggler).
// ---------------------------------------------------------------------------
__global__ __launch_bounds__(256) void gate_cross_mfma_kernel(
    const float* __restrict__ y3d, const float* __restrict__ f2d,
    const int* __restrict__ nn_idx,
    const float* __restrict__ Wg, const float* __restrict__ bg,
    const float* __restrict__ Wc, const float* __restrict__ bc,
    const short* __restrict__ WpF,
    short* __restrict__ p2dbf, float* __restrict__ cross2d)
{
  constexpr int RS = 296;
  __shared__ short g1S[32 * RS];
  __shared__ short g2S[32 * RS];
  __shared__ float yS[32][C3];
  const int tid = threadIdx.x;
  const int lane = tid & 63;
  const int w = tid >> 6;
  const int lm = lane & 15;
  const int quad = lane >> 4;
  const int base = blockIdx.x * 32;

  // zero the CP..288 pad columns
  for (int e = tid; e < 32 * 32; e += 256) {
    int r = e >> 5, cc = 256 + (e & 31);
    if (cc >= CP) {
      g1S[r * RS + cc] = 0;
      g2S[r * RS + cc] = 0;
    }
  }

  // uniform neighbor indices for all 32 rows
  int ix[32];
  #pragma unroll
  for (int r = 0; r < 32; ++r) ix[r] = nn_idx[base + r];

  // issue ALL 32 f2d gathers up front (independent, stay in flight)
  const int c = tid;
  float f[32];
  #pragma unroll
  for (int r = 0; r < 32; ++r)
    f[r] = (ix[r] >= 0) ? f2d[(size_t)ix[r] * CP + c] : 0.f;

  // tail-column gather (threads 0..95 cover r in [0,32) x cc in [0,3))
  float ftail = 0.f;
  int tr = 0, tcc = 0;
  if (tid < 96) {
    tr = tid / 3; tcc = tid - tr * 3;
    if (ix[tr] >= 0) ftail = f2d[(size_t)ix[tr] * CP + 256 + tcc];
  }

  // stage y3d rows cooperatively (contiguous 2KB)
  for (int e = tid; e < 32 * C3; e += 256)
    ((float*)yS)[e] = y3d[(size_t)base * C3 + e];

  float wg[16], wc[16];
  #pragma unroll
  for (int ci = 0; ci < 16; ++ci) {
    wg[ci] = Wg[ci * CP + c];
    wc[ci] = Wc[ci * CP + c];
  }
  const float bgv = bg[c], bcv = bc[c];

  __syncthreads();   // yS ready; f[] loads still in flight where not yet used

  #pragma unroll
  for (int r = 0; r < 32; ++r) {
    float a1 = bgv, a2 = bcv;
    #pragma unroll
    for (int ci = 0; ci < 16; ++ci) {
      float yv = yS[r][ci];
      a1 = fmaf(yv, wg[ci], a1);
      a2 = fmaf(yv, wc[ci], a2);
    }
    g1S[r * RS + c] = bf16r(fmaxf(a1, 0.f) * f[r]);
    g2S[r * RS + c] = bf16r(fmaxf(a2, 0.f) * f[r]);
  }

  if (tid < 96) {
    const int c2 = 256 + tcc;
    float a1 = bg[c2], a2 = bc[c2];
    #pragma unroll
    for (int ci = 0; ci < 16; ++ci) {
      float yv = yS[tr][ci];
      a1 = fmaf(yv, Wg[ci * CP + c2], a1);
      a2 = fmaf(yv, Wc[ci * CP + c2], a2);
    }
    g1S[tr * RS + c2] = bf16r(fmaxf(a1, 0.f) * ftail);
    g2S[tr * RS + c2] = bf16r(fmaxf(a2, 0.f) * ftail);
  }
  __syncthreads();

  const int gsel = w & 1;
  const int mt = w >> 1;
  const short* gS = gsel ? g2S : g1S;
  f32x4 acc[4];
  #pragma unroll
  for (int t = 0; t < 4; ++t) {
    f32x4 z = {0.f, 0.f, 0.f, 0.f};
    acc[t] = z;
  }
  #pragma unroll
  for (int q = 0; q < 9; ++q) {
    short8 af = *(const short8*)&gS[(mt * 16 + lm) * RS + q * 32 + quad * 8];
    #pragma unroll
    for (int t = 0; t < 4; ++t) {
      short8 bf = *(const short8*)&WpF[(((q * 4 + t) * 64) + lane) * 8];
      acc[t] = __builtin_amdgcn_mfma_f32_16x16x32_bf16(af, bf, acc[t], 0, 0, 0);
    }
  }
  #pragma unroll
  for (int t = 0; t < 4; ++t) {
    const int cc = t * 16 + lm;
    #pragma unroll
    for (int rg = 0; rg < 4; ++rg) {
      const int row = base + mt * 16 + quad * 4 + rg;
      float v = acc[t][rg];
      if (gsel == 0)
        p2dbf[(size_t)row * C2 + cc] = bf16r(v);
      else
        cross2d[(size_t)row * C2 + cc] = v;
    }
  }
}

// ---------------------------------------------------------------------------
// conv_pipe: wave-autonomous subm-conv, gather DIRECTLY into MFMA A-frags,
// MT=1 (16 rows/wave), depth-6 rotating register pipeline with
// sched_barrier(0) fences so the compiler cannot re-sink the gathers
// (round-2 VGPR=80 proved it collapsed the depth-3 MT=2 pipeline).
// idx prefetched 12 k-offsets ahead (L1-hot, stride-27 per row).
// 27 = 4*6 + 3: main loop kk=0..18 step 6, 3-phase tail.
//
// MODE 0: bn_relu -> fp32    MODE 1: bn_relu -> bf16
// MODE 2: relu(bn)+res(stride 64) -> fp32 mix[:,16+c] + bf16 mixbf
// MODE 3: relu(bn+res) -> fp32 + bf16    MODE 4: relu(bn+res) -> bf16
// ---------------------------------------------------------------------------
template <int CIN, int COUT_, int MODE>
__global__ __launch_bounds__(64, 3) void conv_pipe_kernel(
    const short* __restrict__ finbf, const int* __restrict__ nbr, int nrows,
    const short* __restrict__ WbfF, const float* __restrict__ gamma,
    const float* __restrict__ beta, const float* __restrict__ resf,
    float* __restrict__ outf, short* __restrict__ outbf)
{
  constexpr int KC = (CIN + 31) / 32;   // 32-wide k-chunks per row
  constexpr int DCH = CIN / 8;          // real 16B chunks per row
  constexpr int NT = COUT_ / 16;
  constexpr int D = 6;                  // pipeline depth (k-offsets in flight)

  const int lane = threadIdx.x;
  const int lm = lane & 15;
  const int quad = lane >> 4;
  const int base = blockIdx.x * 16;
  const int row = base + lm;
  const bool rok = row < nrows;

  f32x4 acc[NT];
  #pragma unroll
  for (int t = 0; t < NT; ++t) {
    f32x4 z = {0.f, 0.f, 0.f, 0.f};
    acc[t] = z;
  }

  const short8 zero8 = {0, 0, 0, 0, 0, 0, 0, 0};
  short8 pa[D][KC];
  int id[D];

  auto loadIdx = [&](int k) -> int {
    return (rok && k < KOFF) ? nbr[(size_t)row * KOFF + k] : -1;
  };
  auto loadA = [&](short8 (&p)[KC], int idx) {
    const int safe = (idx < 0) ? 0 : idx;
    const short* src = finbf + (size_t)safe * CIN;
    #pragma unroll
    for (int q = 0; q < KC; ++q) {
      const int ch = q * 4 + quad;
      short8 v = zero8;
      if (idx >= 0 && ch < DCH) v = *(const short8*)(src + ch * 8);
      p[q] = v;
    }
  };
  auto computeK = [&](const short8 (&p)[KC], int k) {
    const short* wb = WbfF + (size_t)(k * KC * NT) * 512 + lane * 8;
    #pragma unroll
    for (int q = 0; q < KC; ++q) {
      #pragma unroll
      for (int t = 0; t < NT; ++t) {
        short8 bfr = *(const short8*)(wb + (q * NT + t) * 512);
        acc[t] = __builtin_amdgcn_mfma_f32_16x16x32_bf16(p[q], bfr, acc[t], 0, 0, 0);
      }
    }
  };

  // ---- prologue: fill all D slots (k=0..5), prefetch idx for k=6..11 ----
  #pragma unroll
  for (int j = 0; j < D; ++j) {
    int ixt = loadIdx(j);
    loadA(pa[j], ixt);
    id[j] = loadIdx(j + D);
  }
  __builtin_amdgcn_sched_barrier(0);

  // ---- main loop: 4 groups of 6 phases (k = 0..23), refill k+6 ----
  for (int kk = 0; kk < 24; kk += 6) {
    #pragma unroll
    for (int j = 0; j < D; ++j) {
      computeK(pa[j], kk + j);
      __builtin_amdgcn_sched_barrier(0);
      loadA(pa[j], id[j]);                 // gather k = kk+j+6 (zeros if -1)
      id[j] = loadIdx(kk + j + 2 * D);     // idx for k = kk+j+12
      __builtin_amdgcn_sched_barrier(0);
    }
  }
  // ---- tail: k = 24, 25, 26 ----
  #pragma unroll
  for (int j = 0; j < 3; ++j) computeK(pa[j], 24 + j);

  // ---- epilogue ----
  {
    const int rbase = base + quad * 4;
    #pragma unroll
    for (int t = 0; t < NT; ++t) {
      const int cc = t * 16 + lm;
      float g = gamma[cc], b = beta[cc];
      #pragma unroll
      for (int rg = 0; rg < 4; ++rg) {
        int orow = rbase + rg;
        if (orow >= nrows) continue;
        float v = acc[t][rg];
        if (MODE == 0) {
          outf[(size_t)orow * COUT_ + cc] = fmaxf(fmaf(v, g, b), 0.f);
        } else if (MODE == 1) {
          outbf[(size_t)orow * COUT_ + cc] = bf16r(fmaxf(fmaf(v, g, b), 0.f));
        } else if (MODE == 2) {
          float o = fmaxf(fmaf(v, g, b), 0.f) + resf[(size_t)orow * C2 + cc];
          outf[(size_t)orow * CM + 16 + cc] = o;
          outbf[(size_t)orow * CM + 16 + cc] = bf16r(o);
        } else if (MODE == 3) {
          float o = fmaxf(fmaf(v, g, b) + resf[(size_t)orow * COUT_ + cc], 0.f);
          outf[(size_t)orow * COUT_ + cc] = o;
          outbf[(size_t)orow * COUT_ + cc] = bf16r(o);
        } else {
          float o = fmaxf(fmaf(v, g, b) + resf[(size_t)orow * COUT_ + cc], 0.f);
          outbf[(size_t)orow * COUT_ + cc] = bf16r(o);
        }
      }
    }
  }
}

// ---------------------------------------------------------------------------
extern "C" void kernel_launch(void* const* d_in, const int* in_sizes, int n_in,
                              void* d_out, int out_size, void* d_ws, size_t ws_size,
                              hipStream_t stream) {
  const float* x3d  = (const float*)d_in[0];
  const float* f2d  = (const float*)d_in[1];
  const int*   nn   = (const int*)d_in[2];
  const int*   nbr  = (const int*)d_in[3];
  const int*   nbds = (const int*)d_in[4];
  const float* W3d  = (const float*)d_in[5];
  const float* g3d  = (const float*)d_in[6];
  const float* b3d  = (const float*)d_in[7];
  const float* Wg   = (const float*)d_in[8];
  const float* bg   = (const float*)d_in[9];
  const float* Wc   = (const float*)d_in[10];
  const float* bc   = (const float*)d_in[11];
  const float* Wp   = (const float*)d_in[12];
  const float* W2d  = (const float*)d_in[13];
  const float* g2d  = (const float*)d_in[14];
  const float* b2d  = (const float*)d_in[15];
  const float* Wm1  = (const float*)d_in[16];
  const float* gm1  = (const float*)d_in[17];
  const float* bm1  = (const float*)d_in[18];
  const float* Wm2  = (const float*)d_in[19];
  const float* gm2  = (const float*)d_in[20];
  const float* bm2  = (const float*)d_in[21];
  const float* Wa1  = (const float*)d_in[22];
  const float* ga1  = (const float*)d_in[23];
  const float* ba1  = (const float*)d_in[24];
  const float* Wa2  = (const float*)d_in[25];
  const float* ga2  = (const float*)d_in[26];
  const float* ba2  = (const float*)d_in[27];
  const float* Wds  = (const float*)d_in[28];
  const float* gds  = (const float*)d_in[29];
  const float* bds  = (const float*)d_in[30];

  const size_t N = NPTS;
  float* ws = (float*)d_ws;
  float* y3d     = ws;                    // N*16
  short* p2dbf   = (short*)(ws + N * 16); // N*64 bf16
  float* cross2d = ws + N * 48;           // N*64
  float* mix     = ws + N * 112;          // N*80
  short* mixbf   = (short*)(ws + N * 192);// N*80 bf16
  short* tmp1bf  = (short*)(ws + N * 232);// N*80 bf16
  float* hbuf    = ws + N * 272;          // N*80
  short* hbufbf  = (short*)(ws + N * 352);// N*80 bf16
  short* abufbf  = (short*)ws;            // N*80 bf16 (reuses y3d+p2dbf)
  // fragment-ordered bf16 weights at tail
  short* wtail  = (short*)(ws + N * 392);
  short* WbfF2d = wtail;                   // 27*2*4*512 = 110592
  short* WbfFm1 = WbfF2d + 110592;         // 27*3*5*512 = 207360
  short* WbfFm2 = WbfFm1 + 207360;
  short* WbfFa1 = WbfFm2 + 207360;
  short* WbfFa2 = WbfFa1 + 207360;
  short* WbfFds = WbfFa2 + 207360;         // 27*3*6*512 = 248832
  short* WpF    = WbfFds + 248832;         // 18432

  // ---- weight prep ----
  wfrag_kernel<<<(110592 + 255) / 256, 256, 0, stream>>>(W2d, WbfF2d, 64, 64, 2);
  wfrag_kernel<<<(207360 + 255) / 256, 256, 0, stream>>>(Wm1, WbfFm1, 80, 80, 3);
  wfrag_kernel<<<(207360 + 255) / 256, 256, 0, stream>>>(Wm2, WbfFm2, 80, 80, 3);
  wfrag_kernel<<<(207360 + 255) / 256, 256, 0, stream>>>(Wa1, WbfFa1, 80, 80, 3);
  wfrag_kernel<<<(207360 + 255) / 256, 256, 0, stream>>>(Wa2, WbfFa2, 80, 80, 3);
  wfrag_kernel<<<(248832 + 255) / 256, 256, 0, stream>>>(Wds, WbfFds, 80, 96, 3);
  wpfrag_kernel<<<(9 * 4 * 64 * 8 + 255) / 256, 256, 0, stream>>>(Wp, WpF);

  conv3d_bnrelu_kernel<<<NPTS / 16, 256, 0, stream>>>(x3d, nbr, W3d, g3d, b3d,
                                                      y3d, mix, mixbf);
  gate_cross_mfma_kernel<<<NPTS / 32, 256, 0, stream>>>(y3d, f2d, nn, Wg, bg,
                                                        Wc, bc, WpF, p2dbf,
                                                        cross2d);

  const int gridW = (NPTS + 15) / 16;    // 5000 one-wave blocks
  conv_pipe_kernel<64, 64, 2><<<gridW, 64, 0, stream>>>(
      p2dbf, nbr, NPTS, WbfF2d, g2d, b2d, cross2d, mix, mixbf);
  conv_pipe_kernel<80, 80, 1><<<gridW, 64, 0, stream>>>(
      mixbf, nbr, NPTS, WbfFm1, gm1, bm1, nullptr, nullptr, tmp1bf);
  conv_pipe_kernel<80, 80, 3><<<gridW, 64, 0, stream>>>(
      tmp1bf, nbr, NPTS, WbfFm2, gm2, bm2, mix, hbuf, hbufbf);
  conv_pipe_kernel<80, 80, 1><<<gridW, 64, 0, stream>>>(
      hbufbf, nbr, NPTS, WbfFa1, ga1, ba1, nullptr, nullptr, tmp1bf);
  conv_pipe_kernel<80, 80, 4><<<gridW, 64, 0, stream>>>(
      tmp1bf, nbr, NPTS, WbfFa2, ga2, ba2, hbuf, nullptr, abufbf);

  const int gridDS = (NDPTS + 15) / 16;  // 625
  conv_pipe_kernel<80, 96, 0><<<gridDS, 64, 0, stream>>>(
      abufbf, nbds, NDPTS, WbfFds, gds, bds, nullptr, (float*)d_out, nullptr);
}

// Round 4
// 1039.701 us; speedup vs baseline: 1.9178x; 1.9178x over previous
//
#include <hip/hip_runtime.h>

#define NPTS 80000
#define MPTS 150000
#define NDPTS 10000
#define KOFF 27
#define C3 16
#define CP 259
#define C2 64
#define CM 80
#define CO 96

typedef __attribute__((ext_vector_type(8))) short short8;
typedef __attribute__((ext_vector_type(4))) float f32x4;

__device__ inline short bf16r(float f) {
  union { float f; unsigned u; } x{f};
  unsigned r = (x.u + 0x7fffu + ((x.u >> 16) & 1u)) >> 16;
  return (short)r;
}

// ---------------------------------------------------------------------------
// Weight prep: W[k][ci][n] fp32 -> fragment-ordered bf16
// WbfF[((k*KC+q)*NT+t)*512 + lane*8 + j], B-frag element:
// ci = q*32 + (lane>>4)*8 + j, n = t*16 + (lane&15); ci >= CIN zero-padded.
// ---------------------------------------------------------------------------
__global__ void wfrag_kernel(const float* __restrict__ W, short* __restrict__ WbfF,
                             int CIN, int COUT_, int KC) {
  const int NT = COUT_ / 16;
  int i = blockIdx.x * 256 + threadIdx.x;
  int total = KOFF * KC * NT * 512;
  if (i >= total) return;
  int j = i & 7, lane = (i >> 3) & 63;
  int rest = i >> 9;
  int t = rest % NT; rest /= NT;
  int q = rest % KC;
  int k = rest / KC;
  int ci = q * 32 + (lane >> 4) * 8 + j;
  int n = t * 16 + (lane & 15);
  float v = (ci < CIN) ? W[((size_t)k * CIN + ci) * COUT_ + n] : 0.f;
  WbfF[i] = bf16r(v);
}

// ---------------------------------------------------------------------------
// Wp prep: fp32 [259][64] -> bf16 fragment-ordered [q][t][lane][8], K->288.
// ---------------------------------------------------------------------------
__global__ void wpfrag_kernel(const float* __restrict__ Wp, short* __restrict__ WpF) {
  int i = blockIdx.x * 256 + threadIdx.x;
  if (i >= 9 * 4 * 64 * 8) return;
  int j = i & 7, lane = (i >> 3) & 63, t = (i >> 9) & 3, q = i >> 11;
  int k = q * 32 + (lane >> 4) * 8 + j;
  int n = t * 16 + (lane & 15);
  WpF[i] = (k < CP) ? bf16r(Wp[(size_t)k * C2 + n]) : (short)0;
}

// ---------------------------------------------------------------------------
// Kernel 1: conv3d (16->16) + bn_relu -> y3d fp32, mix[:, :16], mixbf[:, :16].
// (round-2 version, verbatim: the round-3 "one-barrier dbuf" rewrite spilled
// to scratch — VGPR 256, WRITE_SIZE 1.34 GB, 809 us.  Reverted.)
// ---------------------------------------------------------------------------
__global__ __launch_bounds__(256) void conv3d_bnrelu_kernel(
    const float* __restrict__ x3d, const int* __restrict__ nbr,
    const float* __restrict__ W3d, const float* __restrict__ g3d,
    const float* __restrict__ b3d, float* __restrict__ y3d,
    float* __restrict__ mix, short* __restrict__ mixbf)
{
  __shared__ float wS[KOFF * C3 * C3];
  __shared__ float fS[16][C3];
  const int tid = threadIdx.x;
  const int base = blockIdx.x * 16;
  for (int e = tid; e < KOFF * C3 * C3; e += 256) wS[e] = W3d[e];
  const int r = tid >> 4, c = tid & 15;
  const int row = base + r;
  float acc = 0.f;
  for (int k = 0; k < KOFF; ++k) {
    int idx = nbr[row * KOFF + k];
    float fv = (idx >= 0) ? x3d[idx * C3 + c] : 0.f;
    __syncthreads();
    fS[r][c] = fv;
    __syncthreads();
    const float* wk = &wS[k * C3 * C3];
    #pragma unroll
    for (int ci = 0; ci < C3; ++ci)
      acc = fmaf(fS[r][ci], wk[ci * C3 + c], acc);
  }
  float v = fmaxf(fmaf(acc, g3d[c], b3d[c]), 0.f);
  y3d[row * C3 + c] = v;
  mix[row * CM + c] = v;
  mixbf[row * CM + c] = bf16r(v);
}

// ---------------------------------------------------------------------------
// Kernel 2: gate/cross fusion. v2: all 32 f2d gathers issued up front
// (8KB in flight per wave), y3d staged to LDS cooperatively, 3-column tail
// parallelized across 96 threads.
// ---------------------------------------------------------------------------
__global__ __launch_bounds__(256) void gate_cross_mfma_kernel(
    const float* __restrict__ y3d, const float* __restrict__ f2d,
    const int* __restrict__ nn_idx,
    const float* __restrict__ Wg, const float* __restrict__ bg,
    const float* __restrict__ Wc, const float* __restrict__ bc,
    const short* __restrict__ WpF,
    short* __restrict__ p2dbf, float* __restrict__ cross2d)
{
  constexpr int RS = 296;
  __shared__ short g1S[32 * RS];
  __shared__ short g2S[32 * RS];
  __shared__ float yS[32][C3];
  const int tid = threadIdx.x;
  const int lane = tid & 63;
  const int w = tid >> 6;
  const int lm = lane & 15;
  const int quad = lane >> 4;
  const int base = blockIdx.x * 32;

  // zero the CP..288 pad columns
  for (int e = tid; e < 32 * 32; e += 256) {
    int r = e >> 5, cc = 256 + (e & 31);
    if (cc >= CP) {
      g1S[r * RS + cc] = 0;
      g2S[r * RS + cc] = 0;
    }
  }

  // uniform neighbor indices for all 32 rows
  int ix[32];
  #pragma unroll
  for (int r = 0; r < 32; ++r) ix[r] = nn_idx[base + r];

  // issue ALL 32 f2d gathers up front (independent, stay in flight)
  const int c = tid;
  float f[32];
  #pragma unroll
  for (int r = 0; r < 32; ++r)
    f[r] = (ix[r] >= 0) ? f2d[(size_t)ix[r] * CP + c] : 0.f;

  // tail-column gather (threads 0..95 cover r in [0,32) x cc in [0,3))
  float ftail = 0.f;
  int tr = 0, tcc = 0;
  if (tid < 96) {
    tr = tid / 3; tcc = tid - tr * 3;
    if (ix[tr] >= 0) ftail = f2d[(size_t)ix[tr] * CP + 256 + tcc];
  }

  // stage y3d rows cooperatively (contiguous 2KB)
  for (int e = tid; e < 32 * C3; e += 256)
    ((float*)yS)[e] = y3d[(size_t)base * C3 + e];

  float wg[16], wc[16];
  #pragma unroll
  for (int ci = 0; ci < 16; ++ci) {
    wg[ci] = Wg[ci * CP + c];
    wc[ci] = Wc[ci * CP + c];
  }
  const float bgv = bg[c], bcv = bc[c];

  __syncthreads();   // yS ready

  #pragma unroll
  for (int r = 0; r < 32; ++r) {
    float a1 = bgv, a2 = bcv;
    #pragma unroll
    for (int ci = 0; ci < 16; ++ci) {
      float yv = yS[r][ci];
      a1 = fmaf(yv, wg[ci], a1);
      a2 = fmaf(yv, wc[ci], a2);
    }
    g1S[r * RS + c] = bf16r(fmaxf(a1, 0.f) * f[r]);
    g2S[r * RS + c] = bf16r(fmaxf(a2, 0.f) * f[r]);
  }

  if (tid < 96) {
    const int c2 = 256 + tcc;
    float a1 = bg[c2], a2 = bc[c2];
    #pragma unroll
    for (int ci = 0; ci < 16; ++ci) {
      float yv = yS[tr][ci];
      a1 = fmaf(yv, Wg[ci * CP + c2], a1);
      a2 = fmaf(yv, Wc[ci * CP + c2], a2);
    }
    g1S[tr * RS + c2] = bf16r(fmaxf(a1, 0.f) * ftail);
    g2S[tr * RS + c2] = bf16r(fmaxf(a2, 0.f) * ftail);
  }
  __syncthreads();

  const int gsel = w & 1;
  const int mt = w >> 1;
  const short* gS = gsel ? g2S : g1S;
  f32x4 acc[4];
  #pragma unroll
  for (int t = 0; t < 4; ++t) {
    f32x4 z = {0.f, 0.f, 0.f, 0.f};
    acc[t] = z;
  }
  #pragma unroll
  for (int q = 0; q < 9; ++q) {
    short8 af = *(const short8*)&gS[(mt * 16 + lm) * RS + q * 32 + quad * 8];
    #pragma unroll
    for (int t = 0; t < 4; ++t) {
      short8 bf = *(const short8*)&WpF[(((q * 4 + t) * 64) + lane) * 8];
      acc[t] = __builtin_amdgcn_mfma_f32_16x16x32_bf16(af, bf, acc[t], 0, 0, 0);
    }
  }
  #pragma unroll
  for (int t = 0; t < 4; ++t) {
    const int cc = t * 16 + lm;
    #pragma unroll
    for (int rg = 0; rg < 4; ++rg) {
      const int row = base + mt * 16 + quad * 4 + rg;
      float v = acc[t][rg];
      if (gsel == 0)
        p2dbf[(size_t)row * C2 + cc] = bf16r(v);
      else
        cross2d[(size_t)row * C2 + cc] = v;
    }
  }
}

// ---------------------------------------------------------------------------
// Wave-autonomous no-LDS subm-conv: gather DIRECTLY into MFMA A-fragments.
// Round-4: MT=1 (16 rows/wave) -> grid 5000 one-wave blocks.  Round-2 showed
// occupancy was GRID-limited (25.8% = 2500 blocks/256 CU), not VGPR-limited;
// doubling resident waves doubles in-flight gathers for this latency-bound
// kernel.  Depth-3 rotating prefetch (27 = 9*3), no sched_barriers (round 3
// proved over-constraining the schedule + registers regresses).
// VGPR budget ~85 (3 bufs x KC x 4 + acc 20) -> fits 4 waves/SIMD at the
// __launch_bounds__(64,4) cap of 128.
//
// MODE 0: bn_relu -> fp32    MODE 1: bn_relu -> bf16
// MODE 2: relu(bn)+res(stride 64) -> fp32 mix[:,16+c] + bf16 mixbf
// MODE 3: relu(bn+res) -> fp32 + bf16    MODE 4: relu(bn+res) -> bf16
// ---------------------------------------------------------------------------
template <int CIN, int COUT_, int MODE>
__global__ __launch_bounds__(64, 4) void conv_nolds_kernel(
    const short* __restrict__ finbf, const int* __restrict__ nbr, int nrows,
    const short* __restrict__ WbfF, const float* __restrict__ gamma,
    const float* __restrict__ beta, const float* __restrict__ resf,
    float* __restrict__ outf, short* __restrict__ outbf)
{
  constexpr int KC = (CIN + 31) / 32;   // 32-wide k-chunks per row
  constexpr int DCH = CIN / 8;          // real 16B chunks per row
  constexpr int NT = COUT_ / 16;

  const int lane = threadIdx.x;
  const int lm = lane & 15;
  const int quad = lane >> 4;
  const int base = blockIdx.x * 16;
  const int row = base + lm;
  const bool rok = row < nrows;

  f32x4 acc[NT];
  #pragma unroll
  for (int t = 0; t < NT; ++t) {
    f32x4 z = {0.f, 0.f, 0.f, 0.f};
    acc[t] = z;
  }

  const short8 zero8 = {0, 0, 0, 0, 0, 0, 0, 0};

  auto loadIdx = [&](int k) -> int {
    return (rok && k < KOFF) ? nbr[(size_t)row * KOFF + k] : -1;
  };
  auto loadA = [&](short8 (&p)[KC], int idx) {
    const int safe = (idx < 0) ? 0 : idx;     // in-bounds address always
    const short* src = finbf + (size_t)safe * CIN;
    #pragma unroll
    for (int q = 0; q < KC; ++q) {
      const int ch = q * 4 + quad;
      short8 v = zero8;
      if (ch < DCH) v = *(const short8*)(src + ch * 8);
      p[q] = (idx >= 0) ? v : zero8;
    }
  };
  auto computeK = [&](const short8 (&p)[KC], int k) {
    const short* wb = WbfF + (size_t)(k * KC * NT) * 512 + lane * 8;
    #pragma unroll
    for (int q = 0; q < KC; ++q) {
      #pragma unroll
      for (int t = 0; t < NT; ++t) {
        short8 bfr = *(const short8*)(wb + (q * NT + t) * 512);
        acc[t] = __builtin_amdgcn_mfma_f32_16x16x32_bf16(p[q], bfr, acc[t], 0, 0, 0);
      }
    }
  };

  // ---- depth-3 software pipeline over k (27 = 9*3, no tail) ----
  int ia, ib, ic;
  short8 paA[KC], paB[KC], paC[KC];

  ia = loadIdx(0); ib = loadIdx(1); ic = loadIdx(2);
  loadA(paA, ia); ia = loadIdx(3);
  loadA(paB, ib); ib = loadIdx(4);

  for (int kk = 0; kk < KOFF; kk += 3) {
    loadA(paC, ic); ic = loadIdx(kk + 5);
    computeK(paA, kk);
    loadA(paA, ia); ia = loadIdx(kk + 6);   // A(kk+3); k>=27 -> idx=-1 -> zeros
    computeK(paB, kk + 1);
    loadA(paB, ib); ib = loadIdx(kk + 7);   // A(kk+4)
    computeK(paC, kk + 2);
  }

  // ---- epilogue ----
  {
    const int rbase = base + quad * 4;
    #pragma unroll
    for (int t = 0; t < NT; ++t) {
      const int cc = t * 16 + lm;
      float g = gamma[cc], b = beta[cc];
      #pragma unroll
      for (int rg = 0; rg < 4; ++rg) {
        int orow = rbase + rg;
        if (orow >= nrows) continue;
        float v = acc[t][rg];
        if (MODE == 0) {
          outf[(size_t)orow * COUT_ + cc] = fmaxf(fmaf(v, g, b), 0.f);
        } else if (MODE == 1) {
          outbf[(size_t)orow * COUT_ + cc] = bf16r(fmaxf(fmaf(v, g, b), 0.f));
        } else if (MODE == 2) {
          float o = fmaxf(fmaf(v, g, b), 0.f) + resf[(size_t)orow * C2 + cc];
          outf[(size_t)orow * CM + 16 + cc] = o;
          outbf[(size_t)orow * CM + 16 + cc] = bf16r(o);
        } else if (MODE == 3) {
          float o = fmaxf(fmaf(v, g, b) + resf[(size_t)orow * COUT_ + cc], 0.f);
          outf[(size_t)orow * COUT_ + cc] = o;
          outbf[(size_t)orow * COUT_ + cc] = bf16r(o);
        } else {
          float o = fmaxf(fmaf(v, g, b) + resf[(size_t)orow * COUT_ + cc], 0.f);
          outbf[(size_t)orow * COUT_ + cc] = bf16r(o);
        }
      }
    }
  }
}

// ---------------------------------------------------------------------------
extern "C" void kernel_launch(void* const* d_in, const int* in_sizes, int n_in,
                              void* d_out, int out_size, void* d_ws, size_t ws_size,
                              hipStream_t stream) {
  const float* x3d  = (const float*)d_in[0];
  const float* f2d  = (const float*)d_in[1];
  const int*   nn   = (const int*)d_in[2];
  const int*   nbr  = (const int*)d_in[3];
  const int*   nbds = (const int*)d_in[4];
  const float* W3d  = (const float*)d_in[5];
  const float* g3d  = (const float*)d_in[6];
  const float* b3d  = (const float*)d_in[7];
  const float* Wg   = (const float*)d_in[8];
  const float* bg   = (const float*)d_in[9];
  const float* Wc   = (const float*)d_in[10];
  const float* bc   = (const float*)d_in[11];
  const float* Wp   = (const float*)d_in[12];
  const float* W2d  = (const float*)d_in[13];
  const float* g2d  = (const float*)d_in[14];
  const float* b2d  = (const float*)d_in[15];
  const float* Wm1  = (const float*)d_in[16];
  const float* gm1  = (const float*)d_in[17];
  const float* bm1  = (const float*)d_in[18];
  const float* Wm2  = (const float*)d_in[19];
  const float* gm2  = (const float*)d_in[20];
  const float* bm2  = (const float*)d_in[21];
  const float* Wa1  = (const float*)d_in[22];
  const float* ga1  = (const float*)d_in[23];
  const float* ba1  = (const float*)d_in[24];
  const float* Wa2  = (const float*)d_in[25];
  const float* ga2  = (const float*)d_in[26];
  const float* ba2  = (const float*)d_in[27];
  const float* Wds  = (const float*)d_in[28];
  const float* gds  = (const float*)d_in[29];
  const float* bds  = (const float*)d_in[30];

  const size_t N = NPTS;
  float* ws = (float*)d_ws;
  float* y3d     = ws;                    // N*16
  short* p2dbf   = (short*)(ws + N * 16); // N*64 bf16
  float* cross2d = ws + N * 48;           // N*64
  float* mix     = ws + N * 112;          // N*80
  short* mixbf   = (short*)(ws + N * 192);// N*80 bf16
  short* tmp1bf  = (short*)(ws + N * 232);// N*80 bf16
  float* hbuf    = ws + N * 272;          // N*80
  short* hbufbf  = (short*)(ws + N * 352);// N*80 bf16
  short* abufbf  = (short*)ws;            // N*80 bf16 (reuses y3d+p2dbf)
  // fragment-ordered bf16 weights at tail
  short* wtail  = (short*)(ws + N * 392);
  short* WbfF2d = wtail;                   // 27*2*4*512 = 110592
  short* WbfFm1 = WbfF2d + 110592;         // 27*3*5*512 = 207360
  short* WbfFm2 = WbfFm1 + 207360;
  short* WbfFa1 = WbfFm2 + 207360;
  short* WbfFa2 = WbfFa1 + 207360;
  short* WbfFds = WbfFa2 + 207360;         // 27*3*6*512 = 248832
  short* WpF    = WbfFds + 248832;         // 18432

  // ---- weight prep ----
  wfrag_kernel<<<(110592 + 255) / 256, 256, 0, stream>>>(W2d, WbfF2d, 64, 64, 2);
  wfrag_kernel<<<(207360 + 255) / 256, 256, 0, stream>>>(Wm1, WbfFm1, 80, 80, 3);
  wfrag_kernel<<<(207360 + 255) / 256, 256, 0, stream>>>(Wm2, WbfFm2, 80, 80, 3);
  wfrag_kernel<<<(207360 + 255) / 256, 256, 0, stream>>>(Wa1, WbfFa1, 80, 80, 3);
  wfrag_kernel<<<(207360 + 255) / 256, 256, 0, stream>>>(Wa2, WbfFa2, 80, 80, 3);
  wfrag_kernel<<<(248832 + 255) / 256, 256, 0, stream>>>(Wds, WbfFds, 80, 96, 3);
  wpfrag_kernel<<<(9 * 4 * 64 * 8 + 255) / 256, 256, 0, stream>>>(Wp, WpF);

  conv3d_bnrelu_kernel<<<NPTS / 16, 256, 0, stream>>>(x3d, nbr, W3d, g3d, b3d,
                                                      y3d, mix, mixbf);
  gate_cross_mfma_kernel<<<NPTS / 32, 256, 0, stream>>>(y3d, f2d, nn, Wg, bg,
                                                        Wc, bc, WpF, p2dbf,
                                                        cross2d);

  const int gridW = (NPTS + 15) / 16;    // 5000 one-wave blocks
  conv_nolds_kernel<64, 64, 2><<<gridW, 64, 0, stream>>>(
      p2dbf, nbr, NPTS, WbfF2d, g2d, b2d, cross2d, mix, mixbf);
  conv_nolds_kernel<80, 80, 1><<<gridW, 64, 0, stream>>>(
      mixbf, nbr, NPTS, WbfFm1, gm1, bm1, nullptr, nullptr, tmp1bf);
  conv_nolds_kernel<80, 80, 3><<<gridW, 64, 0, stream>>>(
      tmp1bf, nbr, NPTS, WbfFm2, gm2, bm2, mix, hbuf, hbufbf);
  conv_nolds_kernel<80, 80, 1><<<gridW, 64, 0, stream>>>(
      hbufbf, nbr, NPTS, WbfFa1, ga1, ba1, nullptr, nullptr, tmp1bf);
  conv_nolds_kernel<80, 80, 4><<<gridW, 64, 0, stream>>>(
      tmp1bf, nbr, NPTS, WbfFa2, ga2, ba2, hbuf, nullptr, abufbf);

  const int gridDS = (NDPTS + 15) / 16;  // 625
  conv_nolds_kernel<80, 96, 0><<<gridDS, 64, 0, stream>>>(
      abufbf, nbds, NDPTS, WbfFds, gds, bds, nullptr, (float*)d_out, nullptr);
}